// Round 7
// baseline (506.107 us; speedup 1.0000x reference)
//
#include <hip/hip_runtime.h>

typedef _Float16 f16x8 __attribute__((ext_vector_type(8)));
typedef float    f32x4 __attribute__((ext_vector_type(4)));

#define NSTEP 512
#define BTB 8       // batches per block (half tile; cols 8..15 of MFMA feed zeros)
#define KS 104      // Act row stride in f16 (52 dw; 16B-aligned rows, uniform bank spread)

__device__ __forceinline__ float sig_(float v) {
    return __builtin_amdgcn_rcpf(1.0f + __expf(-v));
}
// overflow-safe, clamp-free: 1 - 2/(e^{2v}+1)
__device__ __forceinline__ float tanh_(float v) {
    return 1.0f - 2.0f * __builtin_amdgcn_rcpf(__expf(v + v) + 1.0f);
}
// rotate within each 16-lane row by 8: lane m <-> m^8 (full-rate VALU, no LDS)
__device__ __forceinline__ float dpp_ror8(float v) {
    int i = __builtin_bit_cast(int, v);
    i = __builtin_amdgcn_mov_dpp(i, 0x128, 0xF, 0xF, false);   // row_ror:8
    return __builtin_bit_cast(float, i);
}

// 512 threads = 8 waves, grid 512 = 2 blocks/CU (de-phased!), 8 batches/block.
// Wave w owns tiles {2w,2w+1}: units u0=8w+q (tt=0), u1=8w+4+q (tt=1); tile-row
// = usub*4+gate so acc[r] = gate r of one unit. B-op cols = batch (0..7 real,
// 8..15 zero — m>=8 lanes skip the ds_read, exec-masked).
// After the f16 2-pass combine, DPP row_ror:8 moves unit-1 gates from lane
// (q,m<8) to lane (q,m+8): every lane does exactly ONE activation (10 trans).
// c-state: lane (q,m<8) owns (u0, b=m); lane (q,m>=8) owns (u1, b=m-8).
__global__ __launch_bounds__(512, 4) void lstm_mfma_kernel(
    const float* __restrict__ x,     const float* __restrict__ Wemb,
    const float* __restrict__ Wih1,  const float* __restrict__ Whh1,
    const float* __restrict__ b1,    const float* __restrict__ Wih2,
    const float* __restrict__ b2,    const float* __restrict__ Wout,
    const float* __restrict__ bout,  float* __restrict__ out)
{
    __shared__ __align__(16) _Float16 Act[2][BTB][KS];  // [buf][batch][k]  3328 B
    __shared__ __align__(16) float h2tmp[BTB * 64];     //                  2048 B
    __shared__ __align__(16) float h2s[256 * BTB];      //                  8192 B
    __shared__ float part[64 * BTB * 2];                //                  4096 B

    const int t = threadIdx.x;
    const int l = t & 63;
    const int w = t >> 6;        // wave 0..7
    const int m = l & 15;        // tile A-row / B col / D col
    const int q = l >> 4;        // quad: D rows q*4+r
    const int b0 = blockIdx.x * BTB;

    // ---- one-time: weight fragments (f16 hi + lo*2048) into registers ------
    f16x8 wh[2][3], wl[2][3];
    #pragma unroll
    for (int tt = 0; tt < 2; ++tt) {
        const int n = (m & 3) * 64 + (2 * w + tt) * 4 + (m >> 2);  // gate-row
        #pragma unroll
        for (int kc = 0; kc < 3; ++kc) {
            #pragma unroll
            for (int jj = 0; jj < 8; ++jj) {
                int k = kc * 32 + (q << 3) + jj;
                float v = 0.0f;
                if (k < 20)       v = Wih1[n * 20 + k];
                else if (k < 84)  v = Whh1[n * 64 + (k - 20)];
                _Float16 hi = (_Float16)v;
                wh[tt][kc][jj] = hi;
                wl[tt][kc][jj] = (_Float16)((v - (float)hi) * 2048.0f);
            }
        }
    }
    // biases for both of this lane's quad-units (C-init of the hi chain)
    f32x4 bias[2];
    #pragma unroll
    for (int tt = 0; tt < 2; ++tt)
        #pragma unroll
        for (int r = 0; r < 4; ++r)
            bias[tt][r] = b1[r * 64 + (2 * w + tt) * 4 + q];

    // this lane's activation identity after DPP redistribution
    const int myu   = 8 * w + ((m >> 3) << 2) + q;  // unit
    const int myrow = m & 7;                        // batch row in panel

    // ---- emb-writer role: t<160 covers (be=t&7, ee=t>>3), ee 0..19 ---------
    const int be = t & 7;
    const int ee = t >> 3;
    const bool embp = (t < 160);
    const float* xrow = x + (size_t)(b0 + be) * (2 * NSTEP);
    float we0 = 0.f, we1 = 0.f;
    if (embp) { we0 = Wemb[ee * 2]; we1 = Wemb[ee * 2 + 1]; }

    // ---- zero Act (k pads 84..103 stay zero), emb of token 0 ---------------
    for (int idx = t; idx < 2 * BTB * KS; idx += 512)
        ((_Float16*)Act)[idx] = (_Float16)0.0f;
    __syncthreads();
    if (embp) {
        float x0 = xrow[0], x1 = xrow[1];
        Act[0][be][ee] = (_Float16)fmaxf(x0 * we0 + x1 * we1, 0.0f);
    }
    __syncthreads();

    // ---- main recurrence ---------------------------------------------------
    float cst = 0.f;             // one (unit,batch) cell per lane
    int cur = 0;

    for (int step = 0; step < NSTEP; ++step) {
        // prefetch next token (L2-resident)
        float xa = 0.f, xb = 0.f;
        if (embp) {
            int ns = (step + 1 < NSTEP) ? step + 1 : NSTEP - 1;
            xa = xrow[2 * ns]; xb = xrow[2 * ns + 1];
        }

        // B-frags: only m<8 lanes read (rows 8..15 would be zero anyway)
        f16x8 bfr[3] = {};
        if (m < 8) {
            #pragma unroll
            for (int kc = 0; kc < 3; ++kc)
                bfr[kc] = *(const f16x8*)&Act[cur][m][kc * 32 + (q << 3)];
        }

        f32x4 a0[2], a1[2];
        #pragma unroll
        for (int tt = 0; tt < 2; ++tt) {
            a0[tt] = bias[tt];
            a1[tt] = (f32x4){0.f, 0.f, 0.f, 0.f};
        }
        #pragma unroll
        for (int tt = 0; tt < 2; ++tt) {
            #pragma unroll
            for (int kc = 0; kc < 3; ++kc) {
                a0[tt] = __builtin_amdgcn_mfma_f32_16x16x32_f16(wh[tt][kc], bfr[kc], a0[tt], 0, 0, 0);
                a1[tt] = __builtin_amdgcn_mfma_f32_16x16x32_f16(wl[tt][kc], bfr[kc], a1[tt], 0, 0, 0);
            }
        }

        // combine both tiles, then DPP tile-1 gates to the m>=8 half
        float G[4];
        #pragma unroll
        for (int r = 0; r < 4; ++r) {
            float g0 = a0[0][r] + 0x1p-11f * a1[0][r];
            float g1 = a0[1][r] + 0x1p-11f * a1[1][r];
            float gr = dpp_ror8(g1);               // lane m+8 <- lane m's g1
            G[r] = (m < 8) ? g0 : gr;
        }

        // one activation per lane: (myu, batch myrow)
        const int nxt = cur ^ 1;
        {
            float ig = sig_(G[0]);
            float fg = sig_(G[1]);
            float gv = tanh_(G[2]);
            float og = sig_(G[3]);
            cst = fg * cst + ig * gv;
            float hv = og * tanh_(cst);
            Act[nxt][myrow][20 + myu] = (_Float16)hv;
        }
        // emb for next step
        if (embp)
            Act[nxt][be][ee] = (_Float16)fmaxf(xa * we0 + xb * we1, 0.0f);
        __syncthreads();
        cur = nxt;
    }
    // final h (f16) in Act[cur]

    // ---- epilogue: h64 to fp32 (512 values, one per thread) ----------------
    {
        int b = t >> 6, k = t & 63;
        h2tmp[t] = (float)Act[cur][b][20 + k];
    }
    __syncthreads();

    // ---- LSTM2 (single step, h=c=0 -> f-gate irrelevant) -------------------
    {
        const int u = t & 255;
        const int bh0 = (t >> 8) * 4;              // 4 batches per thread-half
        float acci[4], accg[4], acco[4];
        float bi2 = b2[u], bg2 = b2[512 + u], bo2 = b2[768 + u];
        #pragma unroll
        for (int b = 0; b < 4; ++b) { acci[b] = bi2; accg[b] = bg2; acco[b] = bo2; }
        for (int k4 = 0; k4 < 64; k4 += 4) {
            float4 wi = *(const float4*)&Wih2[(size_t)u * 64 + k4];
            float4 wg = *(const float4*)&Wih2[(size_t)(512 + u) * 64 + k4];
            float4 wo = *(const float4*)&Wih2[(size_t)(768 + u) * 64 + k4];
            #pragma unroll
            for (int b = 0; b < 4; ++b) {
                float4 hb = *(const float4*)&h2tmp[(bh0 + b) * 64 + k4];
                acci[b] += wi.x * hb.x + wi.y * hb.y + wi.z * hb.z + wi.w * hb.w;
                accg[b] += wg.x * hb.x + wg.y * hb.y + wg.z * hb.z + wg.w * hb.w;
                acco[b] += wo.x * hb.x + wo.y * hb.y + wo.z * hb.z + wo.w * hb.w;
            }
        }
        #pragma unroll
        for (int b = 0; b < 4; ++b) {
            float c2 = sig_(acci[b]) * tanh_(accg[b]);
            h2s[u * BTB + bh0 + b] = sig_(acco[b]) * tanh_(c2);
        }
    }
    __syncthreads();

    // ---- output projection -------------------------------------------------
    {
        int b = t & 7, grp = t >> 3;               // 64 groups x 4 units
        float p0 = 0.f, p1 = 0.f;
        #pragma unroll
        for (int uu = grp * 4; uu < grp * 4 + 4; ++uu) {
            float hvv = h2s[uu * BTB + b];
            p0 += hvv * Wout[uu];
            p1 += hvv * Wout[256 + uu];
        }
        part[(grp * BTB + b) * 2 + 0] = p0;
        part[(grp * BTB + b) * 2 + 1] = p1;
    }
    __syncthreads();
    if (t < 16) {
        int b = t >> 1, o = t & 1;
        float s0 = bout[o];
        for (int grp = 0; grp < 64; ++grp) s0 += part[(grp * BTB + b) * 2 + o];
        out[(size_t)(b0 + b) * 2 + o] = s0;
    }
}

extern "C" void kernel_launch(void* const* d_in, const int* in_sizes, int n_in,
                              void* d_out, int out_size, void* d_ws, size_t ws_size,
                              hipStream_t stream) {
    const float* x    = (const float*)d_in[0];
    const float* Wemb = (const float*)d_in[1];
    const float* Wih1 = (const float*)d_in[2];
    const float* Whh1 = (const float*)d_in[3];
    const float* b1   = (const float*)d_in[4];
    const float* Wih2 = (const float*)d_in[5];
    // d_in[6] = Whh2: unused (h=c=0 at LSTM2's single step)
    const float* b2   = (const float*)d_in[7];
    const float* Wout = (const float*)d_in[8];
    const float* bout = (const float*)d_in[9];
    float* out = (float*)d_out;

    lstm_mfma_kernel<<<512, 512, 0, stream>>>(
        x, Wemb, Wih1, Whh1, b1, Wih2, b2, Wout, bout, out);
}